// Round 1
// baseline (3940.978 us; speedup 1.0000x reference)
//
#include <hip/hip_runtime.h>
#include <cstdint>
#include <cstddef>

typedef unsigned short u16;
typedef unsigned int u32;
typedef __bf16 bf16x8 __attribute__((ext_vector_type(8)));
typedef float f32x4 __attribute__((ext_vector_type(4)));

__device__ inline float bf2f(u16 h){ union{u32 u; float f;} v; v.u = ((u32)h)<<16; return v.f; }
__device__ inline u16 f2bf(float f){ union{float f; u32 u;} v; v.f=f; u32 r = v.u + 0x7fffu + ((v.u>>16)&1u); return (u16)(r>>16); }

union V16 { uint4 u; bf16x8 b; };

// direct global->LDS, 16B per lane; LDS dest = wave-uniform base + lane*16
__device__ inline void gll16(const u16* g, u16* l){
  __builtin_amdgcn_global_load_lds(
      (const __attribute__((address_space(1))) u32*)g,
      (__attribute__((address_space(3))) u32*)l,
      16, 0, 0);
}

// ---------------- block reduction helpers ----------------
__device__ inline float2 block_red_sum2(float a, float b){
  #pragma unroll
  for (int o=32;o;o>>=1){ a += __shfl_xor(a,o,64); b += __shfl_xor(b,o,64); }
  __shared__ float ta[4], tb[4];
  int w = threadIdx.x>>6;
  if ((threadIdx.x&63)==0){ ta[w]=a; tb[w]=b; }
  __syncthreads();
  float ra = ta[0]+ta[1]+ta[2]+ta[3];
  float rb = tb[0]+tb[1]+tb[2]+tb[3];
  __syncthreads();
  return make_float2(ra, rb);
}

// ---------------- MFMA GEMM: C = A[M,K](bf16) @ Bt[N,K](bf16)^T + epilogue ----------------
// 128x128 tile, BK=64 (two 32-stages, one barrier pair per 64-K), 256 threads = 4 waves.
// flags: 1=+bias[col], 2=+temb[(row/rowdiv)*1280+col], 4=+res[row*ldres+col] (f32), 8=gelu, 16=bf16 out
__global__ __launch_bounds__(256) void kw_gemm(
    const u16* __restrict__ A, const u16* __restrict__ B, void* __restrict__ C,
    int M, int Nclamp, int Nout, int K, int lda, int ldb, int ldc,
    long long sA1, long long sA2, long long sB1, long long sB2, long long sC1, long long sC2,
    int zdiv, int flags,
    const float* __restrict__ bias, const float* __restrict__ temb, int rowdiv,
    const float* __restrict__ res, int ldres)
{
  int z = blockIdx.z;
  int z1 = z / zdiv, z2 = z - z1*zdiv;
  A += z1*sA1 + z2*sA2;
  B += z1*sB1 + z2*sB2;
  long long coff = z1*sC1 + z2*sC2;

  __shared__ u16 As[2*128*32];   // two 32-K stages
  __shared__ u16 Bs[2*128*32];

  int tid  = threadIdx.x;
  int lane = tid & 63, wave = tid >> 6;
  int wm = (wave >> 1) * 64, wn = (wave & 1) * 64;
  int lr = lane & 15, quad = lane >> 4;

  int rowBase = blockIdx.y * 128;
  int colBase = blockIdx.x * 128;

  int srow = wave*16 + (lane >> 2);
  int sseg = ((lane & 3) ^ ((lane >> 3) & 3)) * 8;

  int ar0 = min(rowBase + srow, M-1);
  int ar1 = min(rowBase + 64 + srow, M-1);
  int br0 = min(colBase + srow, Nclamp-1);
  int br1 = min(colBase + 64 + srow, Nclamp-1);
  const u16* ap0 = A + (long long)ar0*lda + sseg;
  const u16* ap1 = A + (long long)ar1*lda + sseg;
  const u16* bp0 = B + (long long)br0*ldb + sseg;
  const u16* bp1 = B + (long long)br1*ldb + sseg;

  u16* lA0 = As + wave*512;
  u16* lA1 = As + 2048 + wave*512;
  u16* lB0 = Bs + wave*512;
  u16* lB1 = Bs + 2048 + wave*512;

  int swz = (lr >> 1) & 3;
  int rdA = lr*32 + ((quad ^ swz) * 8);

  f32x4 acc[4][4];
  #pragma unroll
  for (int mi=0; mi<4; mi++)
    #pragma unroll
    for (int ni=0; ni<4; ni++) acc[mi][ni] = (f32x4){0.f,0.f,0.f,0.f};

  int wmb = wm >> 4;
  int wnb = wn >> 4;

  for (int k0 = 0; k0 < K; k0 += 64) {
    gll16(ap0, lA0);
    gll16(ap1, lA1);
    gll16(bp0, lB0);
    gll16(bp1, lB1);
    gll16(ap0+32, lA0+4096);
    gll16(ap1+32, lA1+4096);
    gll16(bp0+32, lB0+4096);
    gll16(bp1+32, lB1+4096);
    __syncthreads();

    {
      V16 af[4], bf[4];
      #pragma unroll
      for (int mi=0; mi<4; mi++) af[mi].u = *(const uint4*)&As[(wmb + mi)*512 + rdA];
      #pragma unroll
      for (int ni=0; ni<4; ni++) bf[ni].u = *(const uint4*)&Bs[(wnb + ni)*512 + rdA];
      #pragma unroll
      for (int mi=0; mi<4; mi++)
        #pragma unroll
        for (int ni=0; ni<4; ni++)
          acc[mi][ni] = __builtin_amdgcn_mfma_f32_16x16x32_bf16(af[mi].b, bf[ni].b, acc[mi][ni], 0, 0, 0);
    }
    {
      V16 af[4], bf[4];
      #pragma unroll
      for (int mi=0; mi<4; mi++) af[mi].u = *(const uint4*)&As[4096 + (wmb + mi)*512 + rdA];
      #pragma unroll
      for (int ni=0; ni<4; ni++) bf[ni].u = *(const uint4*)&Bs[4096 + (wnb + ni)*512 + rdA];
      #pragma unroll
      for (int mi=0; mi<4; mi++)
        #pragma unroll
        for (int ni=0; ni<4; ni++)
          acc[mi][ni] = __builtin_amdgcn_mfma_f32_16x16x32_bf16(af[mi].b, bf[ni].b, acc[mi][ni], 0, 0, 0);
    }

    __syncthreads();
    ap0 += 64; ap1 += 64; bp0 += 64; bp1 += 64;
  }

  #pragma unroll
  for (int mi=0; mi<4; mi++){
    #pragma unroll
    for (int ni=0; ni<4; ni++){
      #pragma unroll
      for (int rr=0; rr<4; rr++){
        int row = rowBase + wm + mi*16 + quad*4 + rr;
        int col = colBase + wn + ni*16 + lr;
        if (row < M && col < Nout){
          float x = acc[mi][ni][rr];
          if (flags & 1) x += bias[col];
          if (flags & 2) x += temb[(long long)(row/rowdiv)*1280 + col];
          if (flags & 4) x += res[(long long)row*ldres + col];
          if (flags & 8) x = 0.5f*x*(1.f + erff(x*0.70710678118654752f));
          long long o = coff + (long long)row*ldc + col;
          if (flags & 16) ((u16*)C)[o] = f2bf(x);
          else            ((float*)C)[o] = x;
        }
      }
    }
  }
}

// ---------------- 256x256 8-phase counted-vmcnt GEMM (T1+T2+T3+T4+T5) ----------------
// 512 threads = 8 waves (2M x 4N), BK=64, 2 K-tiles per iteration, 128 KiB dynamic LDS.
// LDS regions partitioned by quadrant group:
//   A(buf,g): 128 "rows" i -> global row (i>>6)*128 + g*64 + (i&63)   (g = mh quadrant)
//   B(buf,g): 128 "rows" i -> global col (i>>5)*64  + g*32 + (i&31)   (g = nh quadrant)
// k-swizzle (element, bits 3..5): lds(i, e) = global(i, e ^ ((i&7)<<3)); stage pre-applies it
// on the per-lane GLOBAL source so global_load_lds can write linearly (rule #21).
// Phase schedule per iteration (tiles 2i->buf0, 2i+1->buf1; stages 3 half-tiles ahead):
//  ph1 rd A00,B00  stg A11<-k+64 | ph2 rd B01 stg A00<-k+128 | ph3 rd A01 stg B00<-k+128
//  ph4 stg B01<-k+128 vmcnt(6)   | ph5 rd A10,B10 stg A01<-k+128 | ph6 rd B11 stg A10<-k+192
//  ph7 rd A11 stg B10<-k+192     | ph8 stg B11<-k+192 vmcnt(6)
__global__ __launch_bounds__(512, 2) void kw_gemm256(
    const u16* __restrict__ A, const u16* __restrict__ B, void* __restrict__ C,
    int M, int Nclamp, int Nout, int K, int lda, int ldb, int ldc, int flags,
    const float* __restrict__ bias, const float* __restrict__ temb, int rowdiv,
    const float* __restrict__ res, int ldres)
{
  extern __shared__ u16 lds[];

  int tid = threadIdx.x;
  int lane = tid & 63, wave = tid >> 6;
  int wm = wave >> 2, wn = wave & 3;       // 2 x 4 wave grid
  int lr = lane & 15, quad = lane >> 4;
  int l8 = lane >> 3;
  int ksw = ((lane & 7) ^ l8) << 3;        // stage-side k swizzle (elements)

  // bijective XCD swizzle on x-fast linearized id (m204 variant)
  int gx = gridDim.x, gy = gridDim.y;
  int nwg = gx * gy;
  int orig = blockIdx.y * gx + blockIdx.x;
  int qq = nwg >> 3, rmn = nwg & 7;
  int xcd = orig & 7, loc = orig >> 3;
  int wgid = (xcd < rmn ? xcd * (qq + 1) : rmn * (qq + 1) + (xcd - rmn) * qq) + loc;
  int bx = wgid % gx, by = wgid / gx;

  int rowBase = by * 256, colBase = bx * 256;

  // per-lane staging source pointers [g][r]
  const u16* aS[2][2]; const u16* bS[2][2];
  #pragma unroll
  for (int g=0; g<2; g++){
    #pragma unroll
    for (int r=0; r<2; r++){
      int grow = rowBase + g*64 + r*128 + wave*8 + l8;
      grow = min(grow, M-1);
      aS[g][r] = A + (long long)grow*lda + ksw;
      int gcol = colBase + (r*2 + wm)*64 + g*32 + wn*8 + l8;
      gcol = min(gcol, Nclamp-1);
      bS[g][r] = B + (long long)gcol*ldb + ksw;
    }
  }

  // LDS regions (u16 offsets), 8 x 8192 u16 = 128 KiB
  u16* A00 = lds;          u16* A01 = lds + 8192;
  u16* A10 = lds + 16384;  u16* A11 = lds + 24576;
  u16* B00 = lds + 32768;  u16* B01 = lds + 40960;
  u16* B10 = lds + 49152;  u16* B11 = lds + 57344;

  int dA0 = wave*512, dA1 = 4096 + wave*512;   // wave-uniform LDS dst offsets (u16)

  // fragment read offsets (u16 units within a region)
  int rdA = (wm*64 + lr)*64;
  int rdB = (wn*32 + lr)*64;
  int ksw2 = (lr & 7) << 3;
  int k0off = (quad*8) ^ ksw2;
  int k1off = (32 + quad*8) ^ ksw2;

  f32x4 acc[8][4];
  #pragma unroll
  for (int i=0;i<8;i++)
    #pragma unroll
    for (int j=0;j<4;j++) acc[i][j] = (f32x4){0.f,0.f,0.f,0.f};

#define STG(SRC, G, REG, KO) do{ gll16(SRC[G][0]+(KO), (REG)+dA0); gll16(SRC[G][1]+(KO), (REG)+dA1); }while(0)
#define RD_AF(REG) do{ _Pragma("unroll") for (int m2=0;m2<4;m2++){ \
    af[m2][0].u = *(const uint4*)((REG) + rdA + m2*1024 + k0off); \
    af[m2][1].u = *(const uint4*)((REG) + rdA + m2*1024 + k1off); } }while(0)
#define RD_BF(NB, REG) do{ _Pragma("unroll") for (int n2=0;n2<2;n2++){ \
    bf[(NB)+n2][0].u = *(const uint4*)((REG) + rdB + n2*1024 + k0off); \
    bf[(NB)+n2][1].u = *(const uint4*)((REG) + rdB + n2*1024 + k1off); } }while(0)
#define MM8(MI, NI) do{ _Pragma("unroll") for (int m2=0;m2<4;m2++) \
    _Pragma("unroll") for (int n2=0;n2<2;n2++){ \
      acc[(MI)+m2][(NI)+n2] = __builtin_amdgcn_mfma_f32_16x16x32_bf16(af[m2][0].b, bf[(NI)+n2][0].b, acc[(MI)+m2][(NI)+n2],0,0,0); \
      acc[(MI)+m2][(NI)+n2] = __builtin_amdgcn_mfma_f32_16x16x32_bf16(af[m2][1].b, bf[(NI)+n2][1].b, acc[(MI)+m2][(NI)+n2],0,0,0); } }while(0)
#define BARRIER() asm volatile("s_barrier" ::: "memory")
#define VMCNT6()  asm volatile("s_waitcnt vmcnt(6)" ::: "memory")

  // prologue: buf0 fully (tile0, 8 loads) then buf1 A0,B0,B1 (tile1, 6 loads)
  STG(aS,0,A00,0); STG(bS,0,B00,0); STG(bS,1,B01,0); STG(aS,1,A01,0);
  STG(aS,0,A10,64); STG(bS,0,B10,64); STG(bS,1,B11,64);
  VMCNT6();            // buf0 landed; buf1's 3 half-tiles stay in flight
  BARRIER();

  int nIt = K >> 7;    // K % 128 == 0 required
  for (int it = 0; it < nIt; ++it){
    int kA1 = (it<<7) + 64;
    int kN0 = (it<<7) + 128; if (kN0 >= K) kN0 = 0;   // dummy wrap on last iter
    int kN1 = (it<<7) + 192; if (kN1 >= K) kN1 = 0;

    V16 af[4][2], bf[4][2];

    // ph1: quadrant (mh0,nh0) of buf0
    RD_AF(A00); RD_BF(0, B00); STG(aS,1,A11,kA1);
    BARRIER(); __builtin_amdgcn_s_setprio(1); MM8(0,0); __builtin_amdgcn_s_setprio(0); BARRIER();
    // ph2: (mh0,nh1)
    RD_BF(2, B01); STG(aS,0,A00,kN0);
    BARRIER(); __builtin_amdgcn_s_setprio(1); MM8(0,2); __builtin_amdgcn_s_setprio(0); BARRIER();
    // ph3: (mh1,nh1)
    RD_AF(A01); STG(bS,0,B00,kN0);
    BARRIER(); __builtin_amdgcn_s_setprio(1); MM8(4,2); __builtin_amdgcn_s_setprio(0); BARRIER();
    // ph4: (mh1,nh0)
    STG(bS,1,B01,kN0);
    BARRIER(); __builtin_amdgcn_s_setprio(1); MM8(4,0); __builtin_amdgcn_s_setprio(0);
    VMCNT6(); BARRIER();
    // ph5: (mh0,nh0) of buf1
    RD_AF(A10); RD_BF(0, B10); STG(aS,1,A01,kN0);
    BARRIER(); __builtin_amdgcn_s_setprio(1); MM8(0,0); __builtin_amdgcn_s_setprio(0); BARRIER();
    // ph6: (mh0,nh1)
    RD_BF(2, B11); STG(aS,0,A10,kN1);
    BARRIER(); __builtin_amdgcn_s_setprio(1); MM8(0,2); __builtin_amdgcn_s_setprio(0); BARRIER();
    // ph7: (mh1,nh1)
    RD_AF(A11); STG(bS,0,B10,kN1);
    BARRIER(); __builtin_amdgcn_s_setprio(1); MM8(4,2); __builtin_amdgcn_s_setprio(0); BARRIER();
    // ph8: (mh1,nh0)
    STG(bS,1,B11,kN1);
    BARRIER(); __builtin_amdgcn_s_setprio(1); MM8(4,0); __builtin_amdgcn_s_setprio(0);
    VMCNT6(); BARRIER();
  }

  // drain outstanding LDS-DMA before LDS dealloc, then epilogue
  asm volatile("s_waitcnt vmcnt(0)" ::: "memory");

  #pragma unroll
  for (int mi=0; mi<8; mi++){
    #pragma unroll
    for (int ni=0; ni<4; ni++){
      int col = colBase + wn*64 + (ni>>1)*32 + (ni&1)*16 + lr;
      #pragma unroll
      for (int rr=0; rr<4; rr++){
        int row = rowBase + wm*128 + (mi>>2)*64 + (mi&3)*16 + quad*4 + rr;
        if (row < M && col < Nout){
          float x = acc[mi][ni][rr];
          if (flags & 1) x += bias[col];
          if (flags & 2) x += temb[(long long)(row/rowdiv)*1280 + col];
          if (flags & 4) x += res[(long long)row*ldres + col];
          if (flags & 8) x = 0.5f*x*(1.f + erff(x*0.70710678118654752f));
          long long o = (long long)row*ldc + col;
          if (flags & 16) ((u16*)C)[o] = f2bf(x);
          else            ((float*)C)[o] = x;
        }
      }
    }
  }
#undef STG
#undef RD_AF
#undef RD_BF
#undef MM8
#undef BARRIER
#undef VMCNT6
}

// ---------------- fused flash attention: one block per (b,h) ----------------
__global__ __launch_bounds__(256) void kw_flash(
    const u16* __restrict__ qb, const u16* __restrict__ kvb,
    const u16* __restrict__ Vt, u16* __restrict__ att)
{
  int z = blockIdx.x;
  int b = z / 20, h = z - b*20;
  int tid = threadIdx.x, lane = tid & 63, wave = tid >> 6;
  int lr = lane & 15, quad = lane >> 4;

  __shared__ u16 P[4][16][72];

  const u16* qrow = qb + ((long long)(b*64 + wave*16 + lr))*1280 + h*64;
  V16 aq[2];
  aq[0].u = *(const uint4*)(qrow + quad*8);
  aq[1].u = *(const uint4*)(qrow + 32 + quad*8);

  f32x4 Oacc[4];
  #pragma unroll
  for (int nt=0; nt<4; nt++) Oacc[nt] = (f32x4){0.f,0.f,0.f,0.f};
  float mst[4], lst[4];
  #pragma unroll
  for (int rr=0; rr<4; rr++){ mst[rr] = -3e38f; lst[rr] = 0.f; }

  const u16* kbase = kvb + (long long)b*641*2560 + h*64;
  const u16* vtb   = Vt + (long long)z*64*672;

  for (int kt = 0; kt < 11; kt++){
    int key0 = kt*64;
    V16 bk0[4], bk1[4];
    #pragma unroll
    for (int nt=0; nt<4; nt++){
      int key = min(key0 + nt*16 + lr, 640);
      const u16* kr = kbase + (long long)key*2560;
      bk0[nt].u = *(const uint4*)(kr + quad*8);
      bk1[nt].u = *(const uint4*)(kr + 32 + quad*8);
    }
    f32x4 S[4];
    #pragma unroll
    for (int nt=0; nt<4; nt++){
      S[nt] = (f32x4){0.f,0.f,0.f,0.f};
      S[nt] = __builtin_amdgcn_mfma_f32_16x16x32_bf16(aq[0].b, bk0[nt].b, S[nt], 0,0,0);
      S[nt] = __builtin_amdgcn_mfma_f32_16x16x32_bf16(aq[1].b, bk1[nt].b, S[nt], 0,0,0);
    }
    float rm[4];
    #pragma unroll
    for (int rr=0; rr<4; rr++) rm[rr] = -3e38f;
    #pragma unroll
    for (int nt=0; nt<4; nt++){
      bool valid = (key0 + nt*16 + lr) < 641;
      #pragma unroll
      for (int rr=0; rr<4; rr++){
        float v = valid ? S[nt][rr]*0.125f : -3e38f;
        S[nt][rr] = v;
        rm[rr] = fmaxf(rm[rr], v);
      }
    }
    #pragma unroll
    for (int o=1; o<16; o<<=1)
      #pragma unroll
      for (int rr=0; rr<4; rr++) rm[rr] = fmaxf(rm[rr], __shfl_xor(rm[rr], o, 64));
    float alpha[4];
    #pragma unroll
    for (int rr=0; rr<4; rr++){
      float mn = fmaxf(mst[rr], rm[rr]);
      alpha[rr] = __expf(mst[rr] - mn);
      mst[rr] = mn;
    }
    float rs[4] = {0.f,0.f,0.f,0.f};
    #pragma unroll
    for (int nt=0; nt<4; nt++)
      #pragma unroll
      for (int rr=0; rr<4; rr++){
        float p = __expf(S[nt][rr] - mst[rr]);
        S[nt][rr] = p;
        rs[rr] += p;
      }
    #pragma unroll
    for (int o=1; o<16; o<<=1)
      #pragma unroll
      for (int rr=0; rr<4; rr++) rs[rr] += __shfl_xor(rs[rr], o, 64);
    #pragma unroll
    for (int rr=0; rr<4; rr++) lst[rr] = lst[rr]*alpha[rr] + rs[rr];
    #pragma unroll
    for (int nt=0; nt<4; nt++)
      #pragma unroll
      for (int rr=0; rr<4; rr++)
        P[wave][quad*4+rr][nt*16+lr] = f2bf(S[nt][rr]);
    __syncthreads();
    #pragma unroll
    for (int nt=0; nt<4; nt++)
      #pragma unroll
      for (int rr=0; rr<4; rr++) Oacc[nt][rr] *= alpha[rr];
    V16 ap[2];
    ap[0].u = *(const uint4*)&P[wave][lr][quad*8];
    ap[1].u = *(const uint4*)&P[wave][lr][32 + quad*8];
    #pragma unroll
    for (int nt=0; nt<4; nt++){
      const u16* vr = vtb + (long long)(nt*16 + lr)*672 + key0;
      V16 bv0, bv1;
      bv0.u = *(const uint4*)(vr + quad*8);
      bv1.u = *(const uint4*)(vr + 32 + quad*8);
      Oacc[nt] = __builtin_amdgcn_mfma_f32_16x16x32_bf16(ap[0].b, bv0.b, Oacc[nt], 0,0,0);
      Oacc[nt] = __builtin_amdgcn_mfma_f32_16x16x32_bf16(ap[1].b, bv1.b, Oacc[nt], 0,0,0);
    }
    __syncthreads();
  }
  float inv[4];
  #pragma unroll
  for (int rr=0; rr<4; rr++) inv[rr] = 1.0f / lst[rr];
  #pragma unroll
  for (int nt=0; nt<4; nt++)
    #pragma unroll
    for (int rr=0; rr<4; rr++){
      long long row = b*64 + wave*16 + quad*4 + rr;
      att[row*1280 + h*64 + nt*16 + lr] = f2bf(Oacc[nt][rr]*inv[rr]);
    }
}

// ---------------- transpose f32[K,N] -> bf16[N,K] ----------------
__global__ __launch_bounds__(256) void kw_transpose(const float* __restrict__ in, u16* __restrict__ out,
                                                    int K, int N)
{
  __shared__ u16 t[64][68];
  int k0 = blockIdx.x*64, n0 = blockIdx.y*64;
  int tid = threadIdx.x; int c = tid & 63; int r4 = tid >> 6;
  #pragma unroll
  for (int p = 0; p < 16; p++){
    int kr = r4 + p*4;
    t[kr][c] = f2bf(in[(long long)(k0+kr)*N + n0 + c]);
  }
  __syncthreads();
  #pragma unroll
  for (int p = 0; p < 16; p++){
    int nr = r4 + p*4;
    out[(long long)(n0+nr)*K + k0 + c] = t[c][nr];
  }
}

// ---------------- V transpose ----------------
__global__ __launch_bounds__(256) void kw_vt(const u16* __restrict__ kv, u16* __restrict__ Vt)
{
  int z = blockIdx.x; int kt = blockIdx.y;
  int b = z / 20, hh = z - b*20;
  const u16* src = kv + (long long)b*641*2560 + 1280 + hh*64;
  u16* dst = Vt + (long long)z*64*672;
  __shared__ u16 t[64][68];
  int tid = threadIdx.x; int c = tid & 63; int r4 = tid >> 6;
  #pragma unroll
  for (int p = 0; p < 16; p++){
    int krow = r4 + p*4;
    int key = kt*64 + krow;
    t[krow][c] = (key < 641) ? src[(long long)key*2560 + c] : (u16)0;
  }
  __syncthreads();
  #pragma unroll
  for (int p = 0; p < 16; p++){
    int d = r4 + p*4;
    int key = kt*64 + c;
    if (key < 672) dst[(long long)d*672 + key] = t[c][d];
  }
}

// ---------------- time embedding ----------------
__global__ void kw_timeproj(const float* __restrict__ tstep, float* __restrict__ tproj)
{
  int b = blockIdx.x; int j = threadIdx.x; // 320
  float t = tstep[b];
  int idx = (j < 160) ? j : (j - 160);
  float freq = expf(-9.210340371976184f * (float)idx / 160.0f);
  float a = t * freq;
  tproj[b*320 + j] = (j < 160) ? cosf(a) : sinf(a);
}

__global__ void kw_bias_bcast(const float* __restrict__ bias, float* __restrict__ out, int N)
{
  int b = blockIdx.x; int n = blockIdx.y*256 + threadIdx.x;
  if (n < N) out[(long long)b*N + n] = bias[n];
}

__global__ __launch_bounds__(256) void kw_mlp2(const float* __restrict__ in, const float* __restrict__ W,
    float* __restrict__ out, int K, int N, int kc)
{
  int n = blockIdx.x*256 + threadIdx.x;
  int k0 = blockIdx.y * kc;
  __shared__ float sbuf[32*160];
  for (int idx = threadIdx.x; idx < 32*kc; idx += 256){
    int b = idx / kc, k = idx - b*kc;
    sbuf[idx] = in[(long long)b*K + k0 + k];
  }
  __syncthreads();
  float acc[32];
  #pragma unroll
  for (int b=0;b<32;b++) acc[b]=0.f;
  const float* wp = W + (long long)k0*N + n;
  for (int k=0;k<kc;k++){
    float wv = wp[(long long)k*N];
    #pragma unroll
    for (int b=0;b<32;b++) acc[b] = fmaf(sbuf[b*kc+k], wv, acc[b]);
  }
  #pragma unroll
  for (int b=0;b<32;b++) atomicAdd(out + (long long)b*N + n, acc[b]);
}

__global__ void kw_silu_ip(float* __restrict__ p, int n)
{
  int i = blockIdx.x*256 + threadIdx.x;
  if (i < n){ float x = p[i]; p[i] = x/(1.f+expf(-x)); }
}

__global__ void kw_post_temb(const float* __restrict__ temb, float* __restrict__ silu_t,
                             float* __restrict__ tout, int n)
{
  int i = blockIdx.x*256 + threadIdx.x;
  if (i < n){
    float x = temb[i];
    silu_t[i] = x/(1.f+expf(-x));
    tout[i] = x;
  }
}

__global__ void kw_ada_init(const float* __restrict__ ada_b, float* __restrict__ ada)
{
  int idx = blockIdx.x*256 + threadIdx.x;
  if (idx < 4*32*5120){
    int i = idx / (32*5120);
    int j = idx % 5120;
    ada[idx] = ada_b[i*5120 + j];
  }
}

__global__ __launch_bounds__(256) void kw_ada(const float* __restrict__ silu_t,
    const float* __restrict__ adaW, float* __restrict__ ada)
{
  int jt = blockIdx.x, i = blockIdx.y, ks = blockIdx.z;
  int tid = threadIdx.x;
  int j = jt*256 + tid;
  __shared__ float sbuf[32][160];
  #pragma unroll
  for (int p = 0; p < 20; p++){
    int idx = tid + p*256;
    int b = idx / 160, k = idx - b*160;
    sbuf[b][k] = silu_t[b*1280 + ks*160 + k];
  }
  __syncthreads();
  float acc[32];
  #pragma unroll
  for (int b=0;b<32;b++) acc[b]=0.f;
  const float* wp = adaW + ((long long)i*1280 + ks*160)*5120 + j;
  for (int k=0;k<160;k++){
    float w = wp[(long long)k*5120];
    #pragma unroll
    for (int b=0;b<32;b++) acc[b] = fmaf(sbuf[b][k], w, acc[b]);
  }
  float* op = ada + (long long)i*32*5120 + j;
  for (int b=0;b<32;b++) atomicAdd(op + (long long)b*5120, acc[b]);
}

__global__ void kw_init_lat(const float* __restrict__ l0, float* __restrict__ lat)
{
  int r = blockIdx.x; int q = r & 63;
  #pragma unroll
  for (int i=0;i<5;i++){
    int c = threadIdx.x + i*256;
    lat[(long long)r*1280 + c] = l0[q*1280 + c];
  }
}

__global__ void kw_cvt(const float* __restrict__ in, u16* __restrict__ out, long long n4)
{
  long long i = ((long long)blockIdx.x*256 + threadIdx.x);
  if (i < n4){
    float4 v = *(const float4*)(in + i*4);
    u32 lo = (u32)f2bf(v.x) | ((u32)f2bf(v.y)<<16);
    u32 hi = (u32)f2bf(v.z) | ((u32)f2bf(v.w)<<16);
    uint2 o; o.x = lo; o.y = hi;
    *(uint2*)(out + i*4) = o;
  }
}

__global__ __launch_bounds__(256) void kw_ln_x(const u16* __restrict__ h, u16* __restrict__ cat,
    const float* __restrict__ g, const float* __restrict__ bb)
{
  int r = blockIdx.x;
  int batch = r / 577; int rr = r - batch*577;
  const u16* row = h + (long long)r*1280;
  u16* orow = cat + ((long long)batch*641 + rr)*1280;
  int tid = threadIdx.x;
  float v[5]; float s=0.f, s2=0.f;
  #pragma unroll
  for (int i=0;i<5;i++){ float x = bf2f(row[tid+i*256]); v[i]=x; s+=x; s2+=x*x; }
  float2 r2 = block_red_sum2(s, s2);
  float mean = r2.x * (1.f/1280.f);
  float var  = r2.y * (1.f/1280.f) - mean*mean;
  float rstd = rsqrtf(var + 1e-5f);
  #pragma unroll
  for (int i=0;i<5;i++){
    int c = tid+i*256;
    orow[c] = f2bf((v[i]-mean)*rstd*g[c] + bb[c]);
  }
}

__global__ __launch_bounds__(256) void kw_ln_mod(const float* __restrict__ lat, u16* __restrict__ out1,
    u16* __restrict__ cat, const float* __restrict__ g, const float* __restrict__ bb,
    const float* __restrict__ adabase)
{
  int r = blockIdx.x;
  int b = r >> 6, q = r & 63;
  const float* row = lat + (long long)r*1280;
  const float* ab = adabase + (long long)b*5120;
  int tid = threadIdx.x;
  float v[5]; float s=0.f, s2=0.f;
  #pragma unroll
  for (int i=0;i<5;i++){ float x = row[tid+i*256]; v[i]=x; s+=x; s2+=x*x; }
  float2 r2 = block_red_sum2(s, s2);
  float mean = r2.x * (1.f/1280.f);
  float var  = r2.y * (1.f/1280.f) - mean*mean;
  float rstd = rsqrtf(var + 1e-5f);
  #pragma unroll
  for (int i=0;i<5;i++){
    int c = tid+i*256;
    float sh = ab[c], sc = ab[1280+c];
    float y = ((v[i]-mean)*rstd*g[c] + bb[c])*(1.f+sc) + sh;
    u16 o = f2bf(y);
    out1[(long long)r*1280 + c] = o;
    if (cat) cat[((long long)b*641 + 577 + q)*1280 + c] = o;
  }
}

__global__ __launch_bounds__(256) void kw_ln_out(const float* __restrict__ in, float* __restrict__ out,
    const float* __restrict__ g, const float* __restrict__ bb)
{
  int r = blockIdx.x;
  const float* row = in + (long long)r*2432;
  int tid = threadIdx.x;
  float v[10]; float s=0.f, s2=0.f;
  #pragma unroll
  for (int i=0;i<10;i++){
    int c = tid + i*256;
    float x = (c < 2432) ? row[c] : 0.f;
    v[i]=x; s+=x; s2+=x*x;
  }
  float2 r2 = block_red_sum2(s, s2);
  float mean = r2.x * (1.f/2432.f);
  float var  = r2.y * (1.f/2432.f) - mean*mean;
  float rstd = rsqrtf(var + 1e-5f);
  #pragma unroll
  for (int i=0;i<10;i++){
    int c = tid + i*256;
    if (c < 2432) out[(long long)r*2432 + c] = (v[i]-mean)*rstd*g[c] + bb[c];
  }
}

// ---------------- host ----------------
static inline void launch_gemm(hipStream_t s, const u16* A, const u16* B, void* C,
    int M, int Nclamp, int Nout, int K, int lda, int ldb, int ldc,
    int nz, int zdiv, long long sA1, long long sA2, long long sB1, long long sB2,
    long long sC1, long long sC2, int flags,
    const float* bias = nullptr, const float* temb = nullptr, int rowdiv = 1,
    const float* res = nullptr, int ldres = 0)
{
  dim3 g((Nout+127)/128, (M+127)/128, nz);
  kw_gemm<<<g, dim3(256), 0, s>>>(A,B,C,M,Nclamp,Nout,K,lda,ldb,ldc,
      sA1,sA2,sB1,sB2,sC1,sC2,zdiv,flags,bias,temb,rowdiv,res,ldres);
}

static inline void launch_gemm256(hipStream_t s, const u16* A, const u16* B, void* C,
    int M, int Nclamp, int Nout, int K, int lda, int ldb, int ldc, int flags,
    const float* bias = nullptr, const float* temb = nullptr, int rowdiv = 1,
    const float* res = nullptr, int ldres = 0)
{
  dim3 g((Nout+255)/256, (M+255)/256, 1);
  kw_gemm256<<<g, dim3(512), 131072, s>>>(A,B,C,M,Nclamp,Nout,K,lda,ldb,ldc,flags,
      bias,temb,rowdiv,res,ldres);
}

extern "C" void kernel_launch(void* const* d_in, const int* in_sizes, int n_in,
                              void* d_out, int out_size, void* d_ws, size_t ws_size,
                              hipStream_t stream)
{
  static bool shmem_set = false;
  if (!shmem_set){
    hipFuncSetAttribute((const void*)kw_gemm256,
                        hipFuncAttributeMaxDynamicSharedMemorySize, 131072);
    shmem_set = true;
  }

  const float* x         = (const float*)d_in[0];
  const float* timestep  = (const float*)d_in[1];
  const float* latents0  = (const float*)d_in[2];
  const float* proj_in_W = (const float*)d_in[3];
  const float* proj_in_b = (const float*)d_in[4];
  const float* te1_W     = (const float*)d_in[5];
  const float* te1_b     = (const float*)d_in[6];
  const float* te2_W     = (const float*)d_in[7];
  const float* te2_b     = (const float*)d_in[8];
  const float* ln0_g     = (const float*)d_in[9];
  const float* ln0_b     = (const float*)d_in[10];
  const float* ln1_g     = (const float*)d_in[11];
  const float* ln1_b     = (const float*)d_in[12];
  const float* Wq        = (const float*)d_in[13];
  const float* Wkv       = (const float*)d_in[14];
  const float* Wo        = (const float*)d_in[15];
  const float* ada_W     = (const float*)d_in[16];
  const float* ada_b     = (const float*)d_in[17];
  const float* lnada_g   = (const float*)d_in[18];
  const float* lnada_b   = (const float*)d_in[19];
  const float* Wff1      = (const float*)d_in[20];
  const float* Wff2      = (const float*)d_in[21];
  const float* proj_out_W= (const float*)d_in[22];
  const float* proj_out_b= (const float*)d_in[23];
  const float* norm_out_g= (const float*)d_in[24];
  const float* norm_out_b= (const float*)d_in[25];
  float* out = (float*)d_out;

  const long long MX = 18464;   // B*N
  const long long MC = 20512;   // B*641

  char* w = (char*)d_ws; size_t off = 0;
  auto alloc = [&](size_t bytes)->void*{ void* p = w + off; off += (bytes + 255) & ~(size_t)255; return p; };

  float* tproj  = (float*)alloc(32*320*4);
  float* hidden = (float*)alloc(32*1280*4);
  float* temb   = (float*)alloc(32*1280*4);
  float* silu_t = (float*)alloc(32*1280*4);
  float* ada    = (float*)alloc(4*32*5120*4);
  u16*  h    = (u16*)alloc(MX*1280*2);
  u16*  cat  = (u16*)alloc(MC*1280*2);
  u16*  lm   = (u16*)alloc(2048*1280*2);
  u16*  lm2  = (u16*)alloc(2048*1280*2);
  u16*  qb   = (u16*)alloc(2048*1280*2);
  u16*  att  = (u16*)alloc(2048*1280*2);
  float* lat = (float*)alloc(2048*1280*4);
  u16*  kvb  = (u16*)alloc(MC*2560*2);
  u16*  Vt   = (u16*)alloc((long long)640*64*672*2);
  u16*  WT_pi  = (u16*)alloc(1280*1152*2);
  u16*  WT_po  = (u16*)alloc((long long)2432*1280*2);
  u16*  WqT    = (u16*)alloc(1280*1280*2);
  u16*  WkvT   = (u16*)alloc(2560*1280*2);
  u16*  WoT    = (u16*)alloc(1280*1280*2);
  u16*  Wff1T  = (u16*)alloc((long long)5120*1280*2);
  u16*  Wff2T  = (u16*)alloc((long long)1280*5120*2);
  char* R = (char*)alloc((long long)2048*5120*2 + 4096);
  u16*  xbf    = (u16*)R;
  u16*  ffh    = (u16*)R;
  float* po    = (float*)R;

  if (off > ws_size) return;

  // time embedding MLP
  kw_timeproj<<<dim3(32), dim3(320), 0, stream>>>(timestep, tproj);
  kw_bias_bcast<<<dim3(32,5), dim3(256), 0, stream>>>(te1_b, hidden, 1280);
  kw_mlp2<<<dim3(5,4), dim3(256), 0, stream>>>(tproj, te1_W, hidden, 320, 1280, 80);
  kw_silu_ip<<<dim3(160), dim3(256), 0, stream>>>(hidden, 32*1280);
  kw_bias_bcast<<<dim3(32,5), dim3(256), 0, stream>>>(te2_b, temb, 1280);
  kw_mlp2<<<dim3(5,8), dim3(256), 0, stream>>>(hidden, te2_W, temb, 1280, 1280, 160);
  kw_post_temb<<<dim3(160), dim3(256), 0, stream>>>(temb, silu_t, out + (long long)2048*2432, 32*1280);

  // adaLN embeddings
  kw_ada_init<<<dim3(2560), dim3(256), 0, stream>>>(ada_b, ada);
  kw_ada<<<dim3(20,4,8), dim3(256), 0, stream>>>(silu_t, ada_W, ada);

  // proj_in (256-tile 8-phase)
  kw_cvt<<<dim3((unsigned)((MX*1152/4 + 255)/256)), dim3(256), 0, stream>>>(x, xbf, MX*1152/4);
  kw_transpose<<<dim3(18,20), dim3(256), 0, stream>>>(proj_in_W, WT_pi, 1152, 1280);
  launch_gemm256(stream, xbf, WT_pi, h, (int)MX, 1280, 1280, 1152, 1152, 1152, 1280,
                 1|2|16, proj_in_b, temb, 577);

  kw_init_lat<<<dim3(2048), dim3(256), 0, stream>>>(latents0, lat);
  kw_transpose<<<dim3(20,38), dim3(256), 0, stream>>>(proj_out_W, WT_po, 1280, 2432);

  for (int i = 0; i < 4; i++){
    kw_transpose<<<dim3(20,20), dim3(256), 0, stream>>>(Wq   + (long long)i*1280*1280, WqT,   1280, 1280);
    kw_transpose<<<dim3(20,40), dim3(256), 0, stream>>>(Wkv  + (long long)i*1280*2560, WkvT,  1280, 2560);
    kw_transpose<<<dim3(20,20), dim3(256), 0, stream>>>(Wo   + (long long)i*1280*1280, WoT,   1280, 1280);
    kw_transpose<<<dim3(20,80), dim3(256), 0, stream>>>(Wff1 + (long long)i*1280*5120, Wff1T, 1280, 5120);
    kw_transpose<<<dim3(80,20), dim3(256), 0, stream>>>(Wff2 + (long long)i*5120*1280, Wff2T, 5120, 1280);

    kw_ln_x<<<dim3((unsigned)MX), dim3(256), 0, stream>>>(h, cat, ln0_g + i*1280, ln0_b + i*1280);
    kw_ln_mod<<<dim3(2048), dim3(256), 0, stream>>>(lat, lm, cat, ln1_g + i*1280, ln1_b + i*1280,
                                                    ada + (long long)i*32*5120 + 0);
    // q / kv projections
    launch_gemm(stream, lm,  WqT,  qb,  2048, 1280, 1280, 1280, 1280, 1280, 1280, 1, 1, 0,0,0,0,0,0, 16);
    launch_gemm256(stream, cat, WkvT, kvb, (int)MC, 2560, 2560, 1280, 1280, 1280, 2560, 16);
    // fused flash attention
    kw_vt<<<dim3(640,11), dim3(256), 0, stream>>>(kvb, Vt);
    kw_flash<<<dim3(640), dim3(256), 0, stream>>>(qb, kvb, Vt, att);
    // out projection + residual
    launch_gemm(stream, att, WoT, lat, 2048, 1280, 1280, 1280, 1280, 1280, 1280,
                1, 1, 0,0,0,0,0,0, 4, nullptr, nullptr, 1, lat, 1280);
    // MLP
    kw_ln_mod<<<dim3(2048), dim3(256), 0, stream>>>(lat, lm2, nullptr, lnada_g + i*1280, lnada_b + i*1280,
                                                    ada + (long long)i*32*5120 + 2560);
    launch_gemm256(stream, lm2, Wff1T, ffh, 2048, 5120, 5120, 1280, 1280, 1280, 5120, 8|16);
    launch_gemm(stream, ffh, Wff2T, lat, 2048, 1280, 1280, 5120, 5120, 5120, 1280,
                1, 1, 0,0,0,0,0,0, 4, nullptr, nullptr, 1, lat, 1280);
  }

  // proj_out + final LN
  kw_cvt<<<dim3(2560), dim3(256), 0, stream>>>(lat, lm, 2048*1280/4);
  launch_gemm(stream, lm, WT_po, po, 2048, 2432, 2432, 1280, 1280, 1280, 2432,
              1, 1, 0,0,0,0,0,0, 1, proj_out_b);
  kw_ln_out<<<dim3(2048), dim3(256), 0, stream>>>(po, out, norm_out_g, norm_out_b);
}

// Round 2
// 3938.939 us; speedup vs baseline: 1.0005x; 1.0005x over previous
//
#include <hip/hip_runtime.h>
#include <cstdint>
#include <cstddef>

typedef unsigned short u16;
typedef unsigned int u32;
typedef __bf16 bf16x8 __attribute__((ext_vector_type(8)));
typedef float f32x4 __attribute__((ext_vector_type(4)));

__device__ inline float bf2f(u16 h){ union{u32 u; float f;} v; v.u = ((u32)h)<<16; return v.f; }
__device__ inline u16 f2bf(float f){ union{float f; u32 u;} v; v.f=f; u32 r = v.u + 0x7fffu + ((v.u>>16)&1u); return (u16)(r>>16); }

union V16 { uint4 u; bf16x8 b; };

// direct global->LDS, 16B per lane; LDS dest = wave-uniform base + lane*16
__device__ inline void gll16(const u16* g, u16* l){
  __builtin_amdgcn_global_load_lds(
      (const __attribute__((address_space(1))) u32*)g,
      (__attribute__((address_space(3))) u32*)l,
      16, 0, 0);
}

// ---------------- block reduction helpers ----------------
__device__ inline float2 block_red_sum2(float a, float b){
  #pragma unroll
  for (int o=32;o;o>>=1){ a += __shfl_xor(a,o,64); b += __shfl_xor(b,o,64); }
  __shared__ float ta[4], tb[4];
  int w = threadIdx.x>>6;
  if ((threadIdx.x&63)==0){ ta[w]=a; tb[w]=b; }
  __syncthreads();
  float ra = ta[0]+ta[1]+ta[2]+ta[3];
  float rb = tb[0]+tb[1]+tb[2]+tb[3];
  __syncthreads();
  return make_float2(ra, rb);
}

// ---------------- MFMA GEMM: C = A[M,K](bf16) @ Bt[N,K](bf16)^T + epilogue ----------------
// 128x128 tile, BK=64 (two 32-stages, one barrier pair per 64-K), 256 threads = 4 waves.
// flags: 1=+bias[col], 2=+temb[(row/rowdiv)*1280+col], 4=+res[row*ldres+col] (f32), 8=gelu, 16=bf16 out
__global__ __launch_bounds__(256) void kw_gemm(
    const u16* __restrict__ A, const u16* __restrict__ B, void* __restrict__ C,
    int M, int Nclamp, int Nout, int K, int lda, int ldb, int ldc,
    long long sA1, long long sA2, long long sB1, long long sB2, long long sC1, long long sC2,
    int zdiv, int flags,
    const float* __restrict__ bias, const float* __restrict__ temb, int rowdiv,
    const float* __restrict__ res, int ldres)
{
  int z = blockIdx.z;
  int z1 = z / zdiv, z2 = z - z1*zdiv;
  A += z1*sA1 + z2*sA2;
  B += z1*sB1 + z2*sB2;
  long long coff = z1*sC1 + z2*sC2;

  __shared__ u16 As[2*128*32];   // two 32-K stages
  __shared__ u16 Bs[2*128*32];

  int tid  = threadIdx.x;
  int lane = tid & 63, wave = tid >> 6;
  int wm = (wave >> 1) * 64, wn = (wave & 1) * 64;
  int lr = lane & 15, quad = lane >> 4;

  int rowBase = blockIdx.y * 128;
  int colBase = blockIdx.x * 128;

  int srow = wave*16 + (lane >> 2);
  int sseg = ((lane & 3) ^ ((lane >> 3) & 3)) * 8;

  int ar0 = min(rowBase + srow, M-1);
  int ar1 = min(rowBase + 64 + srow, M-1);
  int br0 = min(colBase + srow, Nclamp-1);
  int br1 = min(colBase + 64 + srow, Nclamp-1);
  const u16* ap0 = A + (long long)ar0*lda + sseg;
  const u16* ap1 = A + (long long)ar1*lda + sseg;
  const u16* bp0 = B + (long long)br0*ldb + sseg;
  const u16* bp1 = B + (long long)br1*ldb + sseg;

  u16* lA0 = As + wave*512;
  u16* lA1 = As + 2048 + wave*512;
  u16* lB0 = Bs + wave*512;
  u16* lB1 = Bs + 2048 + wave*512;

  int swz = (lr >> 1) & 3;
  int rdA = lr*32 + ((quad ^ swz) * 8);

  f32x4 acc[4][4];
  #pragma unroll
  for (int mi=0; mi<4; mi++)
    #pragma unroll
    for (int ni=0; ni<4; ni++) acc[mi][ni] = (f32x4){0.f,0.f,0.f,0.f};

  int wmb = wm >> 4;
  int wnb = wn >> 4;

  for (int k0 = 0; k0 < K; k0 += 64) {
    gll16(ap0, lA0);
    gll16(ap1, lA1);
    gll16(bp0, lB0);
    gll16(bp1, lB1);
    gll16(ap0+32, lA0+4096);
    gll16(ap1+32, lA1+4096);
    gll16(bp0+32, lB0+4096);
    gll16(bp1+32, lB1+4096);
    __syncthreads();

    {
      V16 af[4], bf[4];
      #pragma unroll
      for (int mi=0; mi<4; mi++) af[mi].u = *(const uint4*)&As[(wmb + mi)*512 + rdA];
      #pragma unroll
      for (int ni=0; ni<4; ni++) bf[ni].u = *(const uint4*)&Bs[(wnb + ni)*512 + rdA];
      #pragma unroll
      for (int mi=0; mi<4; mi++)
        #pragma unroll
        for (int ni=0; ni<4; ni++)
          acc[mi][ni] = __builtin_amdgcn_mfma_f32_16x16x32_bf16(af[mi].b, bf[ni].b, acc[mi][ni], 0, 0, 0);
    }
    {
      V16 af[4], bf[4];
      #pragma unroll
      for (int mi=0; mi<4; mi++) af[mi].u = *(const uint4*)&As[4096 + (wmb + mi)*512 + rdA];
      #pragma unroll
      for (int ni=0; ni<4; ni++) bf[ni].u = *(const uint4*)&Bs[4096 + (wnb + ni)*512 + rdA];
      #pragma unroll
      for (int mi=0; mi<4; mi++)
        #pragma unroll
        for (int ni=0; ni<4; ni++)
          acc[mi][ni] = __builtin_amdgcn_mfma_f32_16x16x32_bf16(af[mi].b, bf[ni].b, acc[mi][ni], 0, 0, 0);
    }

    __syncthreads();
    ap0 += 64; ap1 += 64; bp0 += 64; bp1 += 64;
  }

  #pragma unroll
  for (int mi=0; mi<4; mi++){
    #pragma unroll
    for (int ni=0; ni<4; ni++){
      #pragma unroll
      for (int rr=0; rr<4; rr++){
        int row = rowBase + wm + mi*16 + quad*4 + rr;
        int col = colBase + wn + ni*16 + lr;
        if (row < M && col < Nout){
          float x = acc[mi][ni][rr];
          if (flags & 1) x += bias[col];
          if (flags & 2) x += temb[(long long)(row/rowdiv)*1280 + col];
          if (flags & 4) x += res[(long long)row*ldres + col];
          if (flags & 8) x = 0.5f*x*(1.f + erff(x*0.70710678118654752f));
          long long o = coff + (long long)row*ldc + col;
          if (flags & 16) ((u16*)C)[o] = f2bf(x);
          else            ((float*)C)[o] = x;
        }
      }
    }
  }
}

// ---------------- 256x256 8-phase counted-vmcnt GEMM (T1+T2+T3+T4+T5) ----------------
// 512 threads = 8 waves (2M x 4N), BK=64, 2 K-tiles per iteration, 128 KiB dynamic LDS.
// SYNC FIX (round 2): barriers are __builtin_amdgcn_s_barrier() and counted s_waitcnt asm
// carries NO "memory" clobber. A memory-clobber inline asm forces SIInsertWaitcnts to
// emit vmcnt(0) lgkmcnt(0) before it (asm may read LDS written by in-flight DMA), which
// made every phase a full drain in round 1 (m141 failure mode). Clobber-free forms are
// the verified m201 template pattern: loads stay in flight across barriers.
// Phase schedule per iteration (tiles 2i->buf0, 2i+1->buf1; stages 3 half-tiles ahead):
//  ph1 rd A00,B00  stg A11<-k+64 | ph2 rd B01 stg A00<-k+128 | ph3 rd A01 stg B00<-k+128
//  ph4 stg B01<-k+128 vmcnt(6)   | ph5 rd A10,B10 stg A01<-k+128 | ph6 rd B11 stg A10<-k+192
//  ph7 rd A11 stg B10<-k+192     | ph8 stg B11<-k+192 vmcnt(6)
// vmcnt(6) at ph4/ph8 drains exactly the 8 oldest loads = the 4 half-tiles the next
// 4 phases read (steady state 14 outstanding -> 6). Verified by hand r1.
__global__ __launch_bounds__(512, 2) void kw_gemm256(
    const u16* __restrict__ A, const u16* __restrict__ B, void* __restrict__ C,
    int M, int Nclamp, int Nout, int K, int lda, int ldb, int ldc, int flags,
    const float* __restrict__ bias, const float* __restrict__ temb, int rowdiv,
    const float* __restrict__ res, int ldres)
{
  extern __shared__ u16 lds[];

  int tid = threadIdx.x;
  int lane = tid & 63, wave = tid >> 6;
  int wm = wave >> 2, wn = wave & 3;       // 2 x 4 wave grid
  int lr = lane & 15, quad = lane >> 4;
  int l8 = lane >> 3;
  int ksw = ((lane & 7) ^ l8) << 3;        // stage-side k swizzle (elements)

  // bijective XCD swizzle on x-fast linearized id (m204 variant)
  int gx = gridDim.x, gy = gridDim.y;
  int nwg = gx * gy;
  int orig = blockIdx.y * gx + blockIdx.x;
  int qq = nwg >> 3, rmn = nwg & 7;
  int xcd = orig & 7, loc = orig >> 3;
  int wgid = (xcd < rmn ? xcd * (qq + 1) : rmn * (qq + 1) + (xcd - rmn) * qq) + loc;
  int bx = wgid % gx, by = wgid / gx;

  int rowBase = by * 256, colBase = bx * 256;

  // per-lane staging source pointers [g][r]
  const u16* aS[2][2]; const u16* bS[2][2];
  #pragma unroll
  for (int g=0; g<2; g++){
    #pragma unroll
    for (int r=0; r<2; r++){
      int grow = rowBase + g*64 + r*128 + wave*8 + l8;
      grow = min(grow, M-1);
      aS[g][r] = A + (long long)grow*lda + ksw;
      int gcol = colBase + (r*2 + wm)*64 + g*32 + wn*8 + l8;
      gcol = min(gcol, Nclamp-1);
      bS[g][r] = B + (long long)gcol*ldb + ksw;
    }
  }

  // LDS regions (u16 offsets), 8 x 8192 u16 = 128 KiB
  u16* A00 = lds;          u16* A01 = lds + 8192;
  u16* A10 = lds + 16384;  u16* A11 = lds + 24576;
  u16* B00 = lds + 32768;  u16* B01 = lds + 40960;
  u16* B10 = lds + 49152;  u16* B11 = lds + 57344;

  int dA0 = wave*512, dA1 = 4096 + wave*512;   // wave-uniform LDS dst offsets (u16)

  // fragment read offsets (u16 units within a region)
  int rdA = (wm*64 + lr)*64;
  int rdB = (wn*32 + lr)*64;
  int ksw2 = (lr & 7) << 3;
  int k0off = (quad*8) ^ ksw2;
  int k1off = (32 + quad*8) ^ ksw2;

  f32x4 acc[8][4];
  #pragma unroll
  for (int i=0;i<8;i++)
    #pragma unroll
    for (int j=0;j<4;j++) acc[i][j] = (f32x4){0.f,0.f,0.f,0.f};

#define STG(SRC, G, REG, KO) do{ gll16(SRC[G][0]+(KO), (REG)+dA0); gll16(SRC[G][1]+(KO), (REG)+dA1); }while(0)
#define RD_AF(REG) do{ _Pragma("unroll") for (int m2=0;m2<4;m2++){ \
    af[m2][0].u = *(const uint4*)((REG) + rdA + m2*1024 + k0off); \
    af[m2][1].u = *(const uint4*)((REG) + rdA + m2*1024 + k1off); } }while(0)
#define RD_BF(NB, REG) do{ _Pragma("unroll") for (int n2=0;n2<2;n2++){ \
    bf[(NB)+n2][0].u = *(const uint4*)((REG) + rdB + n2*1024 + k0off); \
    bf[(NB)+n2][1].u = *(const uint4*)((REG) + rdB + n2*1024 + k1off); } }while(0)
#define MM8(MI, NI) do{ _Pragma("unroll") for (int m2=0;m2<4;m2++) \
    _Pragma("unroll") for (int n2=0;n2<2;n2++){ \
      acc[(MI)+m2][(NI)+n2] = __builtin_amdgcn_mfma_f32_16x16x32_bf16(af[m2][0].b, bf[(NI)+n2][0].b, acc[(MI)+m2][(NI)+n2],0,0,0); \
      acc[(MI)+m2][(NI)+n2] = __builtin_amdgcn_mfma_f32_16x16x32_bf16(af[m2][1].b, bf[(NI)+n2][1].b, acc[(MI)+m2][(NI)+n2],0,0,0); } }while(0)
#define BARRIER() __builtin_amdgcn_s_barrier()
#define VMCNT6()  asm volatile("s_waitcnt vmcnt(6)")

  // prologue: buf0 fully (tile0, 8 loads) then buf1 A0,B0,B1 (tile1, 6 loads)
  STG(aS,0,A00,0); STG(bS,0,B00,0); STG(bS,1,B01,0); STG(aS,1,A01,0);
  STG(aS,0,A10,64); STG(bS,0,B10,64); STG(bS,1,B11,64);
  VMCNT6();            // buf0 landed; buf1's 3 half-tiles stay in flight
  BARRIER();

  int nIt = K >> 7;    // K % 128 == 0 required
  for (int it = 0; it < nIt; ++it){
    int kA1 = (it<<7) + 64;
    int kN0 = (it<<7) + 128; if (kN0 >= K) kN0 = 0;   // dummy wrap on last iter
    int kN1 = (it<<7) + 192; if (kN1 >= K) kN1 = 0;

    V16 af[4][2], bf[4][2];

    // ph1: quadrant (mh0,nh0) of buf0
    RD_AF(A00); RD_BF(0, B00); STG(aS,1,A11,kA1);
    BARRIER(); __builtin_amdgcn_s_setprio(1); MM8(0,0); __builtin_amdgcn_s_setprio(0); BARRIER();
    // ph2: (mh0,nh1)
    RD_BF(2, B01); STG(aS,0,A00,kN0);
    BARRIER(); __builtin_amdgcn_s_setprio(1); MM8(0,2); __builtin_amdgcn_s_setprio(0); BARRIER();
    // ph3: (mh1,nh1)
    RD_AF(A01); STG(bS,0,B00,kN0);
    BARRIER(); __builtin_amdgcn_s_setprio(1); MM8(4,2); __builtin_amdgcn_s_setprio(0); BARRIER();
    // ph4: (mh1,nh0)
    STG(bS,1,B01,kN0);
    BARRIER(); __builtin_amdgcn_s_setprio(1); MM8(4,0); __builtin_amdgcn_s_setprio(0);
    VMCNT6(); BARRIER();
    // ph5: (mh0,nh0) of buf1
    RD_AF(A10); RD_BF(0, B10); STG(aS,1,A01,kN0);
    BARRIER(); __builtin_amdgcn_s_setprio(1); MM8(0,0); __builtin_amdgcn_s_setprio(0); BARRIER();
    // ph6: (mh0,nh1)
    RD_BF(2, B11); STG(aS,0,A10,kN1);
    BARRIER(); __builtin_amdgcn_s_setprio(1); MM8(0,2); __builtin_amdgcn_s_setprio(0); BARRIER();
    // ph7: (mh1,nh1)
    RD_AF(A11); STG(bS,0,B10,kN1);
    BARRIER(); __builtin_amdgcn_s_setprio(1); MM8(4,2); __builtin_amdgcn_s_setprio(0); BARRIER();
    // ph8: (mh1,nh0)
    STG(bS,1,B11,kN1);
    BARRIER(); __builtin_amdgcn_s_setprio(1); MM8(4,0); __builtin_amdgcn_s_setprio(0);
    VMCNT6(); BARRIER();
  }

  // drain outstanding LDS-DMA before LDS reuse/exit, then epilogue
  asm volatile("s_waitcnt vmcnt(0)");

  #pragma unroll
  for (int mi=0; mi<8; mi++){
    #pragma unroll
    for (int ni=0; ni<4; ni++){
      int col = colBase + wn*64 + (ni>>1)*32 + (ni&1)*16 + lr;
      #pragma unroll
      for (int rr=0; rr<4; rr++){
        int row = rowBase + wm*128 + (mi>>2)*64 + (mi&3)*16 + quad*4 + rr;
        if (row < M && col < Nout){
          float x = acc[mi][ni][rr];
          if (flags & 1) x += bias[col];
          if (flags & 2) x += temb[(long long)(row/rowdiv)*1280 + col];
          if (flags & 4) x += res[(long long)row*ldres + col];
          if (flags & 8) x = 0.5f*x*(1.f + erff(x*0.70710678118654752f));
          long long o = (long long)row*ldc + col;
          if (flags & 16) ((u16*)C)[o] = f2bf(x);
          else            ((float*)C)[o] = x;
        }
      }
    }
  }
#undef STG
#undef RD_AF
#undef RD_BF
#undef MM8
#undef BARRIER
#undef VMCNT6
}

// ---------------- fused flash attention: one block per (b,h) ----------------
__global__ __launch_bounds__(256) void kw_flash(
    const u16* __restrict__ qb, const u16* __restrict__ kvb,
    const u16* __restrict__ Vt, u16* __restrict__ att)
{
  int z = blockIdx.x;
  int b = z / 20, h = z - b*20;
  int tid = threadIdx.x, lane = tid & 63, wave = tid >> 6;
  int lr = lane & 15, quad = lane >> 4;

  __shared__ u16 P[4][16][72];

  const u16* qrow = qb + ((long long)(b*64 + wave*16 + lr))*1280 + h*64;
  V16 aq[2];
  aq[0].u = *(const uint4*)(qrow + quad*8);
  aq[1].u = *(const uint4*)(qrow + 32 + quad*8);

  f32x4 Oacc[4];
  #pragma unroll
  for (int nt=0; nt<4; nt++) Oacc[nt] = (f32x4){0.f,0.f,0.f,0.f};
  float mst[4], lst[4];
  #pragma unroll
  for (int rr=0; rr<4; rr++){ mst[rr] = -3e38f; lst[rr] = 0.f; }

  const u16* kbase = kvb + (long long)b*641*2560 + h*64;
  const u16* vtb   = Vt + (long long)z*64*672;

  for (int kt = 0; kt < 11; kt++){
    int key0 = kt*64;
    V16 bk0[4], bk1[4];
    #pragma unroll
    for (int nt=0; nt<4; nt++){
      int key = min(key0 + nt*16 + lr, 640);
      const u16* kr = kbase + (long long)key*2560;
      bk0[nt].u = *(const uint4*)(kr + quad*8);
      bk1[nt].u = *(const uint4*)(kr + 32 + quad*8);
    }
    f32x4 S[4];
    #pragma unroll
    for (int nt=0; nt<4; nt++){
      S[nt] = (f32x4){0.f,0.f,0.f,0.f};
      S[nt] = __builtin_amdgcn_mfma_f32_16x16x32_bf16(aq[0].b, bk0[nt].b, S[nt], 0,0,0);
      S[nt] = __builtin_amdgcn_mfma_f32_16x16x32_bf16(aq[1].b, bk1[nt].b, S[nt], 0,0,0);
    }
    float rm[4];
    #pragma unroll
    for (int rr=0; rr<4; rr++) rm[rr] = -3e38f;
    #pragma unroll
    for (int nt=0; nt<4; nt++){
      bool valid = (key0 + nt*16 + lr) < 641;
      #pragma unroll
      for (int rr=0; rr<4; rr++){
        float v = valid ? S[nt][rr]*0.125f : -3e38f;
        S[nt][rr] = v;
        rm[rr] = fmaxf(rm[rr], v);
      }
    }
    #pragma unroll
    for (int o=1; o<16; o<<=1)
      #pragma unroll
      for (int rr=0; rr<4; rr++) rm[rr] = fmaxf(rm[rr], __shfl_xor(rm[rr], o, 64));
    float alpha[4];
    #pragma unroll
    for (int rr=0; rr<4; rr++){
      float mn = fmaxf(mst[rr], rm[rr]);
      alpha[rr] = __expf(mst[rr] - mn);
      mst[rr] = mn;
    }
    float rs[4] = {0.f,0.f,0.f,0.f};
    #pragma unroll
    for (int nt=0; nt<4; nt++)
      #pragma unroll
      for (int rr=0; rr<4; rr++){
        float p = __expf(S[nt][rr] - mst[rr]);
        S[nt][rr] = p;
        rs[rr] += p;
      }
    #pragma unroll
    for (int o=1; o<16; o<<=1)
      #pragma unroll
      for (int rr=0; rr<4; rr++) rs[rr] += __shfl_xor(rs[rr], o, 64);
    #pragma unroll
    for (int rr=0; rr<4; rr++) lst[rr] = lst[rr]*alpha[rr] + rs[rr];
    #pragma unroll
    for (int nt=0; nt<4; nt++)
      #pragma unroll
      for (int rr=0; rr<4; rr++)
        P[wave][quad*4+rr][nt*16+lr] = f2bf(S[nt][rr]);
    __syncthreads();
    #pragma unroll
    for (int nt=0; nt<4; nt++)
      #pragma unroll
      for (int rr=0; rr<4; rr++) Oacc[nt][rr] *= alpha[rr];
    V16 ap[2];
    ap[0].u = *(const uint4*)&P[wave][lr][quad*8];
    ap[1].u = *(const uint4*)&P[wave][lr][32 + quad*8];
    #pragma unroll
    for (int nt=0; nt<4; nt++){
      const u16* vr = vtb + (long long)(nt*16 + lr)*672 + key0;
      V16 bv0, bv1;
      bv0.u = *(const uint4*)(vr + quad*8);
      bv1.u = *(const uint4*)(vr + 32 + quad*8);
      Oacc[nt] = __builtin_amdgcn_mfma_f32_16x16x32_bf16(ap[0].b, bv0.b, Oacc[nt], 0,0,0);
      Oacc[nt] = __builtin_amdgcn_mfma_f32_16x16x32_bf16(ap[1].b, bv1.b, Oacc[nt], 0,0,0);
    }
    __syncthreads();
  }
  float inv[4];
  #pragma unroll
  for (int rr=0; rr<4; rr++) inv[rr] = 1.0f / lst[rr];
  #pragma unroll
  for (int nt=0; nt<4; nt++)
    #pragma unroll
    for (int rr=0; rr<4; rr++){
      long long row = b*64 + wave*16 + quad*4 + rr;
      att[row*1280 + h*64 + nt*16 + lr] = f2bf(Oacc[nt][rr]*inv[rr]);
    }
}

// ---------------- transpose f32[K,N] -> bf16[N,K] ----------------
__global__ __launch_bounds__(256) void kw_transpose(const float* __restrict__ in, u16* __restrict__ out,
                                                    int K, int N)
{
  __shared__ u16 t[64][68];
  int k0 = blockIdx.x*64, n0 = blockIdx.y*64;
  int tid = threadIdx.x; int c = tid & 63; int r4 = tid >> 6;
  #pragma unroll
  for (int p = 0; p < 16; p++){
    int kr = r4 + p*4;
    t[kr][c] = f2bf(in[(long long)(k0+kr)*N + n0 + c]);
  }
  __syncthreads();
  #pragma unroll
  for (int p = 0; p < 16; p++){
    int nr = r4 + p*4;
    out[(long long)(n0+nr)*K + k0 + c] = t[c][nr];
  }
}

// ---------------- V transpose ----------------
__global__ __launch_bounds__(256) void kw_vt(const u16* __restrict__ kv, u16* __restrict__ Vt)
{
  int z = blockIdx.x; int kt = blockIdx.y;
  int b = z / 20, hh = z - b*20;
  const u16* src = kv + (long long)b*641*2560 + 1280 + hh*64;
  u16* dst = Vt + (long long)z*64*672;
  __shared__ u16 t[64][68];
  int tid = threadIdx.x; int c = tid & 63; int r4 = tid >> 6;
  #pragma unroll
  for (int p = 0; p < 16; p++){
    int krow = r4 + p*4;
    int key = kt*64 + krow;
    t[krow][c] = (key < 641) ? src[(long long)key*2560 + c] : (u16)0;
  }
  __syncthreads();
  #pragma unroll
  for (int p = 0; p < 16; p++){
    int d = r4 + p*4;
    int key = kt*64 + c;
    if (key < 672) dst[(long long)d*672 + key] = t[c][d];
  }
}

// ---------------- time embedding ----------------
__global__ void kw_timeproj(const float* __restrict__ tstep, float* __restrict__ tproj)
{
  int b = blockIdx.x; int j = threadIdx.x; // 320
  float t = tstep[b];
  int idx = (j < 160) ? j : (j - 160);
  float freq = expf(-9.210340371976184f * (float)idx / 160.0f);
  float a = t * freq;
  tproj[b*320 + j] = (j < 160) ? cosf(a) : sinf(a);
}

__global__ void kw_bias_bcast(const float* __restrict__ bias, float* __restrict__ out, int N)
{
  int b = blockIdx.x; int n = blockIdx.y*256 + threadIdx.x;
  if (n < N) out[(long long)b*N + n] = bias[n];
}

__global__ __launch_bounds__(256) void kw_mlp2(const float* __restrict__ in, const float* __restrict__ W,
    float* __restrict__ out, int K, int N, int kc)
{
  int n = blockIdx.x*256 + threadIdx.x;
  int k0 = blockIdx.y * kc;
  __shared__ float sbuf[32*160];
  for (int idx = threadIdx.x; idx < 32*kc; idx += 256){
    int b = idx / kc, k = idx - b*kc;
    sbuf[idx] = in[(long long)b*K + k0 + k];
  }
  __syncthreads();
  float acc[32];
  #pragma unroll
  for (int b=0;b<32;b++) acc[b]=0.f;
  const float* wp = W + (long long)k0*N + n;
  for (int k=0;k<kc;k++){
    float wv = wp[(long long)k*N];
    #pragma unroll
    for (int b=0;b<32;b++) acc[b] = fmaf(sbuf[b*kc+k], wv, acc[b]);
  }
  #pragma unroll
  for (int b=0;b<32;b++) atomicAdd(out + (long long)b*N + n, acc[b]);
}

__global__ void kw_silu_ip(float* __restrict__ p, int n)
{
  int i = blockIdx.x*256 + threadIdx.x;
  if (i < n){ float x = p[i]; p[i] = x/(1.f+expf(-x)); }
}

__global__ void kw_post_temb(const float* __restrict__ temb, float* __restrict__ silu_t,
                             float* __restrict__ tout, int n)
{
  int i = blockIdx.x*256 + threadIdx.x;
  if (i < n){
    float x = temb[i];
    silu_t[i] = x/(1.f+expf(-x));
    tout[i] = x;
  }
}

__global__ void kw_ada_init(const float* __restrict__ ada_b, float* __restrict__ ada)
{
  int idx = blockIdx.x*256 + threadIdx.x;
  if (idx < 4*32*5120){
    int i = idx / (32*5120);
    int j = idx % 5120;
    ada[idx] = ada_b[i*5120 + j];
  }
}

__global__ __launch_bounds__(256) void kw_ada(const float* __restrict__ silu_t,
    const float* __restrict__ adaW, float* __restrict__ ada)
{
  int jt = blockIdx.x, i = blockIdx.y, ks = blockIdx.z;
  int tid = threadIdx.x;
  int j = jt*256 + tid;
  __shared__ float sbuf[32][160];
  #pragma unroll
  for (int p = 0; p < 20; p++){
    int idx = tid + p*256;
    int b = idx / 160, k = idx - b*160;
    sbuf[b][k] = silu_t[b*1280 + ks*160 + k];
  }
  __syncthreads();
  float acc[32];
  #pragma unroll
  for (int b=0;b<32;b++) acc[b]=0.f;
  const float* wp = adaW + ((long long)i*1280 + ks*160)*5120 + j;
  for (int k=0;k<160;k++){
    float w = wp[(long long)k*5120];
    #pragma unroll
    for (int b=0;b<32;b++) acc[b] = fmaf(sbuf[b][k], w, acc[b]);
  }
  float* op = ada + (long long)i*32*5120 + j;
  for (int b=0;b<32;b++) atomicAdd(op + (long long)b*5120, acc[b]);
}

__global__ void kw_init_lat(const float* __restrict__ l0, float* __restrict__ lat)
{
  int r = blockIdx.x; int q = r & 63;
  #pragma unroll
  for (int i=0;i<5;i++){
    int c = threadIdx.x + i*256;
    lat[(long long)r*1280 + c] = l0[q*1280 + c];
  }
}

__global__ void kw_cvt(const float* __restrict__ in, u16* __restrict__ out, long long n4)
{
  long long i = ((long long)blockIdx.x*256 + threadIdx.x);
  if (i < n4){
    float4 v = *(const float4*)(in + i*4);
    u32 lo = (u32)f2bf(v.x) | ((u32)f2bf(v.y)<<16);
    u32 hi = (u32)f2bf(v.z) | ((u32)f2bf(v.w)<<16);
    uint2 o; o.x = lo; o.y = hi;
    *(uint2*)(out + i*4) = o;
  }
}

__global__ __launch_bounds__(256) void kw_ln_x(const u16* __restrict__ h, u16* __restrict__ cat,
    const float* __restrict__ g, const float* __restrict__ bb)
{
  int r = blockIdx.x;
  int batch = r / 577; int rr = r - batch*577;
  const u16* row = h + (long long)r*1280;
  u16* orow = cat + ((long long)batch*641 + rr)*1280;
  int tid = threadIdx.x;
  float v[5]; float s=0.f, s2=0.f;
  #pragma unroll
  for (int i=0;i<5;i++){ float x = bf2f(row[tid+i*256]); v[i]=x; s+=x; s2+=x*x; }
  float2 r2 = block_red_sum2(s, s2);
  float mean = r2.x * (1.f/1280.f);
  float var  = r2.y * (1.f/1280.f) - mean*mean;
  float rstd = rsqrtf(var + 1e-5f);
  #pragma unroll
  for (int i=0;i<5;i++){
    int c = tid+i*256;
    orow[c] = f2bf((v[i]-mean)*rstd*g[c] + bb[c]);
  }
}

__global__ __launch_bounds__(256) void kw_ln_mod(const float* __restrict__ lat, u16* __restrict__ out1,
    u16* __restrict__ cat, const float* __restrict__ g, const float* __restrict__ bb,
    const float* __restrict__ adabase)
{
  int r = blockIdx.x;
  int b = r >> 6, q = r & 63;
  const float* row = lat + (long long)r*1280;
  const float* ab = adabase + (long long)b*5120;
  int tid = threadIdx.x;
  float v[5]; float s=0.f, s2=0.f;
  #pragma unroll
  for (int i=0;i<5;i++){ float x = row[tid+i*256]; v[i]=x; s+=x; s2+=x*x; }
  float2 r2 = block_red_sum2(s, s2);
  float mean = r2.x * (1.f/1280.f);
  float var  = r2.y * (1.f/1280.f) - mean*mean;
  float rstd = rsqrtf(var + 1e-5f);
  #pragma unroll
  for (int i=0;i<5;i++){
    int c = tid+i*256;
    float sh = ab[c], sc = ab[1280+c];
    float y = ((v[i]-mean)*rstd*g[c] + bb[c])*(1.f+sc) + sh;
    u16 o = f2bf(y);
    out1[(long long)r*1280 + c] = o;
    if (cat) cat[((long long)b*641 + 577 + q)*1280 + c] = o;
  }
}

__global__ __launch_bounds__(256) void kw_ln_out(const float* __restrict__ in, float* __restrict__ out,
    const float* __restrict__ g, const float* __restrict__ bb)
{
  int r = blockIdx.x;
  const float* row = in + (long long)r*2432;
  int tid = threadIdx.x;
  float v[10]; float s=0.f, s2=0.f;
  #pragma unroll
  for (int i=0;i<10;i++){
    int c = tid + i*256;
    float x = (c < 2432) ? row[c] : 0.f;
    v[i]=x; s+=x; s2+=x*x;
  }
  float2 r2 = block_red_sum2(s, s2);
  float mean = r2.x * (1.f/2432.f);
  float var  = r2.y * (1.f/2432.f) - mean*mean;
  float rstd = rsqrtf(var + 1e-5f);
  #pragma unroll
  for (int i=0;i<10;i++){
    int c = tid + i*256;
    if (c < 2432) out[(long long)r*2432 + c] = (v[i]-mean)*rstd*g[c] + bb[c];
  }
}

// ---------------- host ----------------
static inline void launch_gemm(hipStream_t s, const u16* A, const u16* B, void* C,
    int M, int Nclamp, int Nout, int K, int lda, int ldb, int ldc,
    int nz, int zdiv, long long sA1, long long sA2, long long sB1, long long sB2,
    long long sC1, long long sC2, int flags,
    const float* bias = nullptr, const float* temb = nullptr, int rowdiv = 1,
    const float* res = nullptr, int ldres = 0)
{
  dim3 g((Nout+127)/128, (M+127)/128, nz);
  kw_gemm<<<g, dim3(256), 0, s>>>(A,B,C,M,Nclamp,Nout,K,lda,ldb,ldc,
      sA1,sA2,sB1,sB2,sC1,sC2,zdiv,flags,bias,temb,rowdiv,res,ldres);
}

static inline void launch_gemm256(hipStream_t s, const u16* A, const u16* B, void* C,
    int M, int Nclamp, int Nout, int K, int lda, int ldb, int ldc, int flags,
    const float* bias = nullptr, const float* temb = nullptr, int rowdiv = 1,
    const float* res = nullptr, int ldres = 0)
{
  dim3 g((Nout+255)/256, (M+255)/256, 1);
  kw_gemm256<<<g, dim3(512), 131072, s>>>(A,B,C,M,Nclamp,Nout,K,lda,ldb,ldc,flags,
      bias,temb,rowdiv,res,ldres);
}

extern "C" void kernel_launch(void* const* d_in, const int* in_sizes, int n_in,
                              void* d_out, int out_size, void* d_ws, size_t ws_size,
                              hipStream_t stream)
{
  static bool shmem_set = false;
  if (!shmem_set){
    hipFuncSetAttribute((const void*)kw_gemm256,
                        hipFuncAttributeMaxDynamicSharedMemorySize, 131072);
    shmem_set = true;
  }

  const float* x         = (const float*)d_in[0];
  const float* timestep  = (const float*)d_in[1];
  const float* latents0  = (const float*)d_in[2];
  const float* proj_in_W = (const float*)d_in[3];
  const float* proj_in_b = (const float*)d_in[4];
  const float* te1_W     = (const float*)d_in[5];
  const float* te1_b     = (const float*)d_in[6];
  const float* te2_W     = (const float*)d_in[7];
  const float* te2_b     = (const float*)d_in[8];
  const float* ln0_g     = (const float*)d_in[9];
  const float* ln0_b     = (const float*)d_in[10];
  const float* ln1_g     = (const float*)d_in[11];
  const float* ln1_b     = (const float*)d_in[12];
  const float* Wq        = (const float*)d_in[13];
  const float* Wkv       = (const float*)d_in[14];
  const float* Wo        = (const float*)d_in[15];
  const float* ada_W     = (const float*)d_in[16];
  const float* ada_b     = (const float*)d_in[17];
  const float* lnada_g   = (const float*)d_in[18];
  const float* lnada_b   = (const float*)d_in[19];
  const float* Wff1      = (const float*)d_in[20];
  const float* Wff2      = (const float*)d_in[21];
  const float* proj_out_W= (const float*)d_in[22];
  const float* proj_out_b= (const float*)d_in[23];
  const float* norm_out_g= (const float*)d_in[24];
  const float* norm_out_b= (const float*)d_in[25];
  float* out = (float*)d_out;

  const long long MX = 18464;   // B*N
  const long long MC = 20512;   // B*641

  char* w = (char*)d_ws; size_t off = 0;
  auto alloc = [&](size_t bytes)->void*{ void* p = w + off; off += (bytes + 255) & ~(size_t)255; return p; };

  float* tproj  = (float*)alloc(32*320*4);
  float* hidden = (float*)alloc(32*1280*4);
  float* temb   = (float*)alloc(32*1280*4);
  float* silu_t = (float*)alloc(32*1280*4);
  float* ada    = (float*)alloc(4*32*5120*4);
  u16*  h    = (u16*)alloc(MX*1280*2);
  u16*  cat  = (u16*)alloc(MC*1280*2);
  u16*  lm   = (u16*)alloc(2048*1280*2);
  u16*  lm2  = (u16*)alloc(2048*1280*2);
  u16*  qb   = (u16*)alloc(2048*1280*2);
  u16*  att  = (u16*)alloc(2048*1280*2);
  float* lat = (float*)alloc(2048*1280*4);
  u16*  kvb  = (u16*)alloc(MC*2560*2);
  u16*  Vt   = (u16*)alloc((long long)640*64*672*2);
  u16*  WT_pi  = (u16*)alloc(1280*1152*2);
  u16*  WT_po  = (u16*)alloc((long long)2432*1280*2);
  u16*  WqT    = (u16*)alloc(1280*1280*2);
  u16*  WkvT   = (u16*)alloc(2560*1280*2);
  u16*  WoT    = (u16*)alloc(1280*1280*2);
  u16*  Wff1T  = (u16*)alloc((long long)5120*1280*2);
  u16*  Wff2T  = (u16*)alloc((long long)1280*5120*2);
  char* R = (char*)alloc((long long)2048*5120*2 + 4096);
  u16*  xbf    = (u16*)R;
  u16*  ffh    = (u16*)R;
  float* po    = (float*)R;

  if (off > ws_size) return;

  // time embedding MLP
  kw_timeproj<<<dim3(32), dim3(320), 0, stream>>>(timestep, tproj);
  kw_bias_bcast<<<dim3(32,5), dim3(256), 0, stream>>>(te1_b, hidden, 1280);
  kw_mlp2<<<dim3(5,4), dim3(256), 0, stream>>>(tproj, te1_W, hidden, 320, 1280, 80);
  kw_silu_ip<<<dim3(160), dim3(256), 0, stream>>>(hidden, 32*1280);
  kw_bias_bcast<<<dim3(32,5), dim3(256), 0, stream>>>(te2_b, temb, 1280);
  kw_mlp2<<<dim3(5,8), dim3(256), 0, stream>>>(hidden, te2_W, temb, 1280, 1280, 160);
  kw_post_temb<<<dim3(160), dim3(256), 0, stream>>>(temb, silu_t, out + (long long)2048*2432, 32*1280);

  // adaLN embeddings
  kw_ada_init<<<dim3(2560), dim3(256), 0, stream>>>(ada_b, ada);
  kw_ada<<<dim3(20,4,8), dim3(256), 0, stream>>>(silu_t, ada_W, ada);

  // proj_in (256-tile 8-phase)
  kw_cvt<<<dim3((unsigned)((MX*1152/4 + 255)/256)), dim3(256), 0, stream>>>(x, xbf, MX*1152/4);
  kw_transpose<<<dim3(18,20), dim3(256), 0, stream>>>(proj_in_W, WT_pi, 1152, 1280);
  launch_gemm256(stream, xbf, WT_pi, h, (int)MX, 1280, 1280, 1152, 1152, 1152, 1280,
                 1|2|16, proj_in_b, temb, 577);

  kw_init_lat<<<dim3(2048), dim3(256), 0, stream>>>(latents0, lat);
  kw_transpose<<<dim3(20,38), dim3(256), 0, stream>>>(proj_out_W, WT_po, 1280, 2432);

  for (int i = 0; i < 4; i++){
    kw_transpose<<<dim3(20,20), dim3(256), 0, stream>>>(Wq   + (long long)i*1280*1280, WqT,   1280, 1280);
    kw_transpose<<<dim3(20,40), dim3(256), 0, stream>>>(Wkv  + (long long)i*1280*2560, WkvT,  1280, 2560);
    kw_transpose<<<dim3(20,20), dim3(256), 0, stream>>>(Wo   + (long long)i*1280*1280, WoT,   1280, 1280);
    kw_transpose<<<dim3(20,80), dim3(256), 0, stream>>>(Wff1 + (long long)i*1280*5120, Wff1T, 1280, 5120);
    kw_transpose<<<dim3(80,20), dim3(256), 0, stream>>>(Wff2 + (long long)i*5120*1280, Wff2T, 5120, 1280);

    kw_ln_x<<<dim3((unsigned)MX), dim3(256), 0, stream>>>(h, cat, ln0_g + i*1280, ln0_b + i*1280);
    kw_ln_mod<<<dim3(2048), dim3(256), 0, stream>>>(lat, lm, cat, ln1_g + i*1280, ln1_b + i*1280,
                                                    ada + (long long)i*32*5120 + 0);
    // q / kv projections
    launch_gemm(stream, lm,  WqT,  qb,  2048, 1280, 1280, 1280, 1280, 1280, 1280, 1, 1, 0,0,0,0,0,0, 16);
    launch_gemm256(stream, cat, WkvT, kvb, (int)MC, 2560, 2560, 1280, 1280, 1280, 2560, 16);
    // fused flash attention
    kw_vt<<<dim3(640,11), dim3(256), 0, stream>>>(kvb, Vt);
    kw_flash<<<dim3(640), dim3(256), 0, stream>>>(qb, kvb, Vt, att);
    // out projection + residual
    launch_gemm(stream, att, WoT, lat, 2048, 1280, 1280, 1280, 1280, 1280, 1280,
                1, 1, 0,0,0,0,0,0, 4, nullptr, nullptr, 1, lat, 1280);
    // MLP
    kw_ln_mod<<<dim3(2048), dim3(256), 0, stream>>>(lat, lm2, nullptr, lnada_g + i*1280, lnada_b + i*1280,
                                                    ada + (long long)i*32*5120 + 2560);
    launch_gemm256(stream, lm2, Wff1T, ffh, 2048, 5120, 5120, 1280, 1280, 1280, 5120, 8|16);
    launch_gemm(stream, ffh, Wff2T, lat, 2048, 1280, 1280, 5120, 5120, 5120, 1280,
                1, 1, 0,0,0,0,0,0, 4, nullptr, nullptr, 1, lat, 1280);
  }

  // proj_out + final LN
  kw_cvt<<<dim3(2560), dim3(256), 0, stream>>>(lat, lm, 2048*1280/4);
  launch_gemm(stream, lm, WT_po, po, 2048, 2432, 2432, 1280, 1280, 1280, 2432,
              1, 1, 0,0,0,0,0,0, 1, proj_out_b);
  kw_ln_out<<<dim3(2048), dim3(256), 0, stream>>>(po, out, norm_out_g, norm_out_b);
}